// Round 5
// baseline (82.568 us; speedup 1.0000x reference)
//
#include <hip/hip_runtime.h>
#include <math.h>

#define NT 50
#define NC 20
#define NB 64
// blocks per batch: 16 (scale0) + 4 (scale1) + 2 (scale2)
#define BPB 22
#define NBLK (NB * BPB)  // 1408

// anchors / stride per scale
__device__ __constant__ float c_aw[3][3] = {
    {14.5f, 19.5f, 46.625f},
    {1.875f, 3.875f, 3.6875f},
    {0.3125f, 0.5f, 1.03125f}};
__device__ __constant__ float c_ah[3][3] = {
    {11.25f, 24.75f, 40.75f},
    {3.8125f, 2.8125f, 7.4375f},
    {0.40625f, 0.9375f, 0.71875f}};

__global__ __launch_bounds__(256) void yolo_loss_kernel(
    const float* __restrict__ pred0, const float* __restrict__ pred1,
    const float* __restrict__ pred2, const float* __restrict__ boxes,
    const int* __restrict__ cls, float* __restrict__ ws) {
  int bid = blockIdx.x;
  int b = bid / BPB;
  int r = bid % BPB;
  int scale, part, nparts;
  if (r < 16) { scale = 0; part = r; nparts = 16; }
  else if (r < 20) { scale = 1; part = r - 16; nparts = 4; }
  else { scale = 2; part = r - 20; nparts = 2; }

  const int fs = (scale == 0) ? 52 : ((scale == 1) ? 26 : 13);
  const int cells = fs * fs * 3;
  const int planef = cells * 25;  // floats in one (batch,scale) plane
  const float* pred = (scale == 0) ? pred0 : ((scale == 1) ? pred1 : pred2);
  const float* plane = pred + (size_t)b * planef;
  const float invN = 1.0f / (float)(NB * cells);
  const float invNC = invN * (1.0f / (float)NC);

  __shared__ unsigned s_obj[256];  // obj bitmap: ceil(8112/32)=254 words max
  __shared__ int s_cell[NT];
  __shared__ unsigned s_bit[NT];
  __shared__ float s_tcx[NT], s_tcy[NT], s_tww[NT], s_thh[NT];
  __shared__ float s_red[4];

  const int tid = threadIdx.x;

  // clear bitmap
  s_obj[tid] = 0u;
  __syncthreads();

  // ---- per-target prep (identical math to validated R1) ----
  if (tid < NT) {
    const float* bx = boxes + ((size_t)b * NT + tid) * 4;
    float ffs = (float)fs;
    float tbx = bx[0] * ffs;
    float tby = bx[1] * ffs;
    float tw = bx[2] * ffs;
    float th = bx[3] * ffs;
    float bestr = -1.0f;
    int best = 0;
    for (int a = 0; a < 3; ++a) {
      float aw = c_aw[scale][a], ah = c_ah[scale][a];
      float inter = fminf(tw, aw) * fminf(th, ah);
      float uni = tw * th + aw * ah - inter;
      float rr = inter / (uni + 1e-6f);
      if (rr > bestr) { bestr = rr; best = a; }
    }
    int gx = (int)tbx;
    if (gx < 0) gx = 0;
    if (gx > fs - 1) gx = fs - 1;
    int gy = (int)tby;
    if (gy < 0) gy = 0;
    if (gy > fs - 1) gy = fs - 1;
    int cell = (gy * fs + gx) * 3 + best;
    s_cell[tid] = cell;
    s_tcx[tid] = tbx - (float)gx;
    s_tcy[tid] = tby - (float)gy;
    s_tww[tid] = logf(tw / c_aw[scale][best] + 1e-6f);
    s_thh[tid] = logf(th / c_ah[scale][best] + 1e-6f);
    s_bit[tid] = 1u << cls[(size_t)b * NT + tid];
    atomicOr(&s_obj[cell >> 5], 1u << (cell & 31));
  }
  __syncthreads();

  // per-element evaluation
  auto eval = [&](int cell, int ch, float v) -> float {
    bool obj = (s_obj[cell >> 5] >> (cell & 31)) & 1u;
    if (!obj) {
      if (ch != 4) return 0.0f;
      float pc = 1.0f / (1.0f + expf(-v));
      return 0.5f * invN * (-logf(fmaxf(1.0f - pc, 1e-12f)));
    }
    // rare path: obj cell — scan targets (last wins, class-bit union)
    int win = -1;
    unsigned mask = 0u;
    for (int t = 0; t < NT; ++t) {
      if (s_cell[t] == cell) { win = t; mask |= s_bit[t]; }
    }
    if (ch == 0) {
      int gx = (cell / 3) % fs;
      float d = 1.0f / (1.0f + expf(-v)) + (float)gx - s_tcx[win];
      return 5.0f * invN * d * d;
    } else if (ch == 1) {
      int gy = (cell / 3) / fs;
      float d = 1.0f / (1.0f + expf(-v)) + (float)gy - s_tcy[win];
      return 5.0f * invN * d * d;
    } else if (ch == 2) {
      int a = cell % 3;
      float d = expf(v) * c_aw[scale][a] - s_tww[win];
      return 5.0f * invN * d * d;
    } else if (ch == 3) {
      int a = cell % 3;
      float d = expf(v) * c_ah[scale][a] - s_thh[win];
      return 5.0f * invN * d * d;
    } else if (ch == 4) {
      float pc = 1.0f / (1.0f + expf(-v));
      return invN * (-logf(fmaxf(pc, 1e-12f)));
    }
    int c = ch - 5;
    float pc = 1.0f / (1.0f + expf(-v));
    float q = ((mask >> c) & 1u) ? pc : (1.0f - pc);
    return invNC * (-logf(fmaxf(q, 1e-12f)));
  };

  float contrib = 0.0f;

  if (scale < 2) {
    // float4 streaming (plane offsets are 16B-aligned for scale0/1)
    int nf4 = planef >> 2;
    int per = (nf4 + nparts - 1) / nparts;
    int start = part * per;
    int end = start + per;
    if (end > nf4) end = nf4;
    const float4* p4 = (const float4*)plane;
    for (int i = start + tid; i < end; i += 256) {
      float4 v = p4[i];
      int idxr = i * 4;
      int cell = idxr / 25;
      int ch = idxr - cell * 25;
      contrib += eval(cell, ch, v.x);
      if (++ch == 25) { ch = 0; ++cell; }
      contrib += eval(cell, ch, v.y);
      if (++ch == 25) { ch = 0; ++cell; }
      contrib += eval(cell, ch, v.z);
      if (++ch == 25) { ch = 0; ++cell; }
      contrib += eval(cell, ch, v.w);
    }
  } else {
    // scale2 planes start at odd float offsets -> scalar coalesced stream
    int per = (planef + nparts - 1) / nparts;
    int start = part * per;
    int end = start + per;
    if (end > planef) end = planef;
    for (int i = start + tid; i < end; i += 256) {
      float v = plane[i];
      int cell = i / 25;
      int ch = i - cell * 25;
      contrib += eval(cell, ch, v);
    }
  }
  contrib *= (1.0f / 3.0f);

  // ---- block reduction -> per-block partial ----
  for (int off = 32; off > 0; off >>= 1) contrib += __shfl_down(contrib, off);
  if ((tid & 63) == 0) s_red[tid >> 6] = contrib;
  __syncthreads();
  if (tid == 0) ws[bid] = s_red[0] + s_red[1] + s_red[2] + s_red[3];
}

__global__ __launch_bounds__(256) void reduce_kernel(
    const float* __restrict__ ws, float* __restrict__ out) {
  __shared__ float s_red[4];
  int tid = threadIdx.x;
  float v = 0.0f;
  for (int i = tid; i < NBLK; i += 256) v += ws[i];
  for (int off = 32; off > 0; off >>= 1) v += __shfl_down(v, off);
  if ((tid & 63) == 0) s_red[tid >> 6] = v;
  __syncthreads();
  if (tid == 0) out[0] = s_red[0] + s_red[1] + s_red[2] + s_red[3];
}

extern "C" void kernel_launch(void* const* d_in, const int* in_sizes, int n_in,
                              void* d_out, int out_size, void* d_ws, size_t ws_size,
                              hipStream_t stream) {
  const float* pred0 = (const float*)d_in[0];
  const float* pred1 = (const float*)d_in[1];
  const float* pred2 = (const float*)d_in[2];
  const float* boxes = (const float*)d_in[3];
  const int* cls = (const int*)d_in[4];
  float* out = (float*)d_out;
  float* ws = (float*)d_ws;

  yolo_loss_kernel<<<NBLK, 256, 0, stream>>>(pred0, pred1, pred2, boxes, cls, ws);
  reduce_kernel<<<1, 256, 0, stream>>>(ws, out);
}

// Round 6
// 62.362 us; speedup vs baseline: 1.3240x; 1.3240x over previous
//
#include <hip/hip_runtime.h>
#include <math.h>

#define NT 50
#define NC 20
#define NB 64
#define NBLK 2048

// anchors / stride per scale: scale0 fs=52 (masks 6,7,8), scale1 fs=26, scale2 fs=13
__device__ __constant__ float c_aw[3][3] = {
    {14.5f, 19.5f, 46.625f},
    {1.875f, 3.875f, 3.6875f},
    {0.3125f, 0.5f, 1.03125f}};
__device__ __constant__ float c_ah[3][3] = {
    {11.25f, 24.75f, 40.75f},
    {3.8125f, 2.8125f, 7.4375f},
    {0.40625f, 0.9375f, 0.71875f}};

__device__ __forceinline__ float softplus_f(float x) {
  return __logf(1.0f + __expf(x));  // ln(1+e^x), v_exp+v_log fast path
}
__device__ __forceinline__ float sigmoid_f(float x) {
  return 1.0f / (1.0f + __expf(-x));
}

__global__ __launch_bounds__(256) void yolo_loss_kernel(
    const float* __restrict__ pred0, const float* __restrict__ pred1,
    const float* __restrict__ pred2, const float* __restrict__ boxes,
    const int* __restrict__ cls, float* __restrict__ ws) {
  int bid = blockIdx.x;
  int scale, b, part, nparts;
  if (bid < 1536) { scale = 0; b = bid / 24; part = bid % 24; nparts = 24; }
  else if (bid < 1920) { int r = bid - 1536; scale = 1; b = r / 6; part = r % 6; nparts = 6; }
  else { int r = bid - 1920; scale = 2; b = r / 2; part = r % 2; nparts = 2; }

  const int fs = (scale == 0) ? 52 : ((scale == 1) ? 26 : 13);
  const int cells = fs * fs * 3;
  const int planef = cells * 25;
  const float* pred = (scale == 0) ? pred0 : ((scale == 1) ? pred1 : pred2);
  const float* plane = pred + (size_t)b * planef;
  const float invN = 1.0f / (float)(NB * cells);
  const float invNC = invN * (1.0f / (float)NC);

  __shared__ unsigned s_obj[256];  // obj bitmap (max 8112 cells -> 254 words)
  __shared__ int s_cell[NT];
  __shared__ unsigned s_bit[NT];
  __shared__ float s_tcx[NT], s_tcy[NT], s_tww[NT], s_thh[NT];
  __shared__ float s_red[4];

  const int tid = threadIdx.x;
  s_obj[tid] = 0u;
  __syncthreads();

  // ---- per-target prep ----
  if (tid < NT) {
    const float* bx = boxes + ((size_t)b * NT + tid) * 4;
    float ffs = (float)fs;
    float tbx = bx[0] * ffs;
    float tby = bx[1] * ffs;
    float tw = bx[2] * ffs;
    float th = bx[3] * ffs;
    float bestr = -1.0f;
    int best = 0;
    for (int a = 0; a < 3; ++a) {
      float aw = c_aw[scale][a], ah = c_ah[scale][a];
      float inter = fminf(tw, aw) * fminf(th, ah);
      float uni = tw * th + aw * ah - inter;
      float rr = inter / (uni + 1e-6f);
      if (rr > bestr) { bestr = rr; best = a; }
    }
    int gx = (int)tbx;
    if (gx < 0) gx = 0;
    if (gx > fs - 1) gx = fs - 1;
    int gy = (int)tby;
    if (gy < 0) gy = 0;
    if (gy > fs - 1) gy = fs - 1;
    int cell = (gy * fs + gx) * 3 + best;
    s_cell[tid] = cell;
    s_tcx[tid] = tbx - (float)gx;
    s_tcy[tid] = tby - (float)gy;
    s_tww[tid] = __logf(tw / c_aw[scale][best] + 1e-6f);
    s_thh[tid] = __logf(th / c_ah[scale][best] + 1e-6f);
    s_bit[tid] = 1u << cls[(size_t)b * NT + tid];
    atomicOr(&s_obj[cell >> 5], 1u << (cell & 31));
  }
  __syncthreads();

  // full per-element eval (slow path; cheap fast transcendentals)
  auto evalFull = [&](int cell, int k, float v) -> float {
    bool obj = (s_obj[cell >> 5] >> (cell & 31)) & 1u;
    if (!obj) {
      if (k != 4) return 0.0f;
      return 0.5f * invN * softplus_f(v);
    }
    int win = -1;
    unsigned mask = 0u;
    for (int t = 0; t < NT; ++t)
      if (s_cell[t] == cell) { win = t; mask |= s_bit[t]; }
    if (k == 0) {
      int gx = (cell / 3) % fs;
      float d = sigmoid_f(v) + (float)gx - s_tcx[win];
      return 5.0f * invN * d * d;
    } else if (k == 1) {
      int gy = (cell / 3) / fs;
      float d = sigmoid_f(v) + (float)gy - s_tcy[win];
      return 5.0f * invN * d * d;
    } else if (k == 2) {
      float d = __expf(v) * c_aw[scale][cell % 3] - s_tww[win];
      return 5.0f * invN * d * d;
    } else if (k == 3) {
      float d = __expf(v) * c_ah[scale][cell % 3] - s_thh[win];
      return 5.0f * invN * d * d;
    } else if (k == 4) {
      return invN * softplus_f(-v);
    }
    int cc = k - 5;
    float sp = ((mask >> cc) & 1u) ? softplus_f(-v) : softplus_f(v);
    return invNC * sp;
  };

  float contrib = 0.0f;

  if (scale < 2) {
    // planef divisible by 4 and plane 16B-aligned for scales 0,1
    int nf4 = planef >> 2;
    int per = (nf4 + nparts - 1) / nparts;
    int i0 = part * per;
    int i1 = i0 + per;
    if (i1 > nf4) i1 = nf4;
    const float4* p4 = (const float4*)plane;
    int i = i0 + tid;
    if (i < i1) {
      int f = i << 2;
      int cell = f / 25;
      int ch = f - cell * 25;
      for (; i < i1; i += 256) {
        float4 v = p4[i];
        unsigned w0 = s_obj[cell >> 5];
        int c1 = (ch >= 22) ? (cell + 1) : cell;  // last comp's cell
        unsigned w1 = s_obj[c1 >> 5];
        bool anyobj = (((w0 >> (cell & 31)) | (w1 >> (c1 & 31))) & 1u) != 0;
        if (!__any(anyobj)) {
          // noobj: only the conf channel (ch==4) contributes; it exists iff ch in [1,4]
          if (ch >= 1 && ch <= 4) {
            float vc = (ch == 4) ? v.x : ((ch == 3) ? v.y : ((ch == 2) ? v.z : v.w));
            contrib += 0.5f * invN * softplus_f(vc);
          }
        } else {
          int c = cell, k = ch;
          contrib += evalFull(c, k, v.x);
          if (++k == 25) { k = 0; ++c; }
          contrib += evalFull(c, k, v.y);
          if (++k == 25) { k = 0; ++c; }
          contrib += evalFull(c, k, v.z);
          if (++k == 25) { k = 0; ++c; }
          contrib += evalFull(c, k, v.w);
        }
        cell += 40; ch += 24;              // advance 1024 floats
        if (ch >= 25) { ch -= 25; ++cell; }
      }
    }
  } else {
    // scale2 planes are only 4B-aligned: scalar coalesced stream (4.7% of data)
    int per = (planef + nparts - 1) / nparts;
    int s0 = part * per;
    int s1 = s0 + per;
    if (s1 > planef) s1 = planef;
    int i = s0 + tid;
    if (i < s1) {
      int cell = i / 25;
      int ch = i - cell * 25;
      for (; i < s1; i += 256) {
        float v = plane[i];
        bool objb = (s_obj[cell >> 5] >> (cell & 31)) & 1u;
        bool need = objb | (ch == 4);
        if (__any(need)) {
          if (need) contrib += evalFull(cell, ch, v);
        }
        cell += 10; ch += 6;               // advance 256 floats
        if (ch >= 25) { ch -= 25; ++cell; }
      }
    }
  }
  contrib *= (1.0f / 3.0f);

  // ---- block reduction -> per-block partial ----
  for (int off = 32; off > 0; off >>= 1) contrib += __shfl_down(contrib, off);
  if ((tid & 63) == 0) s_red[tid >> 6] = contrib;
  __syncthreads();
  if (tid == 0) ws[bid] = s_red[0] + s_red[1] + s_red[2] + s_red[3];
}

__global__ __launch_bounds__(256) void reduce_kernel(
    const float* __restrict__ ws, float* __restrict__ out) {
  __shared__ float s_red[4];
  int tid = threadIdx.x;
  float v = 0.0f;
  for (int i = tid; i < NBLK; i += 256) v += ws[i];
  for (int off = 32; off > 0; off >>= 1) v += __shfl_down(v, off);
  if ((tid & 63) == 0) s_red[tid >> 6] = v;
  __syncthreads();
  if (tid == 0) out[0] = s_red[0] + s_red[1] + s_red[2] + s_red[3];
}

extern "C" void kernel_launch(void* const* d_in, const int* in_sizes, int n_in,
                              void* d_out, int out_size, void* d_ws, size_t ws_size,
                              hipStream_t stream) {
  const float* pred0 = (const float*)d_in[0];
  const float* pred1 = (const float*)d_in[1];
  const float* pred2 = (const float*)d_in[2];
  const float* boxes = (const float*)d_in[3];
  const int* cls = (const int*)d_in[4];
  float* out = (float*)d_out;
  float* ws = (float*)d_ws;

  yolo_loss_kernel<<<NBLK, 256, 0, stream>>>(pred0, pred1, pred2, boxes, cls, ws);
  reduce_kernel<<<1, 256, 0, stream>>>(ws, out);
}

// Round 7
// 21.916 us; speedup vs baseline: 3.7674x; 2.8455x over previous
//
#include <hip/hip_runtime.h>
#include <math.h>

#define NT 50
#define NC 20
#define NB 64
#define NSTREAM 2016            // 1536 (pred0) + 384 (pred1) + 96 (pred2)
#define NCORR 192               // 3 scales x 64 batches
#define NBLK (NSTREAM + NCORR)  // 2208

// anchors / stride per scale: scale0 fs=52 (masks 6,7,8), scale1 fs=26, scale2 fs=13
__device__ __constant__ float c_aw[3][3] = {
    {14.5f, 19.5f, 46.625f},
    {1.875f, 3.875f, 3.6875f},
    {0.3125f, 0.5f, 1.03125f}};
__device__ __constant__ float c_ah[3][3] = {
    {11.25f, 24.75f, 40.75f},
    {3.8125f, 2.8125f, 7.4375f},
    {0.40625f, 0.9375f, 0.71875f}};
// 1/(NB*cells) per scale: cells = 8112, 2028, 507
__device__ __constant__ float c_invN[3] = {
    1.0f / 519168.0f, 1.0f / 129792.0f, 1.0f / 32448.0f};

__device__ __forceinline__ float softplus_f(float x) {
  return __logf(1.0f + __expf(x));  // -log(1-sigmoid(x)) == softplus(x)
}
__device__ __forceinline__ float sigmoid_f(float x) {
  return 1.0f / (1.0f + __expf(-x));
}

__global__ __launch_bounds__(256) void yolo_main(
    const float* __restrict__ pred0, const float* __restrict__ pred1,
    const float* __restrict__ pred2, const float* __restrict__ boxes,
    const int* __restrict__ cls, float* __restrict__ ws) {
  const int bid = blockIdx.x;
  const int tid = threadIdx.x;
  __shared__ float s_red[4];
  float acc = 0.0f;

  if (bid < NSTREAM) {
    // ---------------- STREAM: every element treated as noobj ----------------
    // Only channel ch==4 (conf) contributes: 0.5*invN*softplus(v).
    int scale, part, nblk, nf4;
    const float* arr;
    if (bid < 1536) { scale = 0; part = bid; nblk = 1536; arr = pred0; nf4 = 3244800; }
    else if (bid < 1920) { scale = 1; part = bid - 1536; nblk = 384; arr = pred1; nf4 = 811200; }
    else { scale = 2; part = bid - 1920; nblk = 96; arr = pred2; nf4 = 202800; }
    const int per = (nf4 + nblk - 1) / nblk;  // 2113
    const int i0 = part * per;
    int i1 = i0 + per;
    if (i1 > nf4) i1 = nf4;
    const float4* p4 = (const float4*)arr;
    int i = i0 + tid;
    if (i < i1) {
      int ch0 = (i * 4) % 25;  // channel of component .x; then incremental
      for (; i < i1; i += 256) {
        float4 v = p4[i];
        // channels of v = ch0..ch0+3; conf (4) present iff ch0 in [1,4]
        if (ch0 >= 1 && ch0 <= 4) {
          float vc = (ch0 == 4) ? v.x : ((ch0 == 3) ? v.y : ((ch0 == 2) ? v.z : v.w));
          acc += softplus_f(vc);
        }
        ch0 += 24;                    // advance 1024 floats: 1024 % 25 == 24
        if (ch0 >= 25) ch0 -= 25;
      }
    }
    acc *= c_invN[scale] * (0.5f / 3.0f);
  } else {
    // -------------- CORRECTION: exact obj-cell terms, minus over-count -----
    const int bid2 = bid - NSTREAM;
    const int scale = bid2 >> 6;  // 0..2
    const int b = bid2 & 63;
    const int fs = (scale == 0) ? 52 : ((scale == 1) ? 26 : 13);
    const int cells = fs * fs * 3;
    const float* arr = (scale == 0) ? pred0 : ((scale == 1) ? pred1 : pred2);
    const float* plane = arr + (size_t)b * cells * 25;
    const float invN = c_invN[scale];
    const float invNC = invN * (1.0f / (float)NC);

    __shared__ int s_cell[NT];
    __shared__ unsigned s_bit[NT];

    int cell = -1, gx = 0, gy = 0, best = 0;
    float tcx = 0.f, tcy = 0.f, tww = 0.f, thh = 0.f;
    if (tid < NT) {
      const float* bx = boxes + ((size_t)b * NT + tid) * 4;
      float ffs = (float)fs;
      float tbx = bx[0] * ffs;
      float tby = bx[1] * ffs;
      float tw = bx[2] * ffs;
      float th = bx[3] * ffs;
      float bestr = -1.0f;
      for (int a = 0; a < 3; ++a) {
        float aw = c_aw[scale][a], ah = c_ah[scale][a];
        float inter = fminf(tw, aw) * fminf(th, ah);
        float uni = tw * th + aw * ah - inter;
        float rr = inter / (uni + 1e-6f);
        if (rr > bestr) { bestr = rr; best = a; }
      }
      gx = (int)tbx;
      if (gx < 0) gx = 0;
      if (gx > fs - 1) gx = fs - 1;
      gy = (int)tby;
      if (gy < 0) gy = 0;
      if (gy > fs - 1) gy = fs - 1;
      cell = (gy * fs + gx) * 3 + best;
      tcx = tbx - (float)gx;
      tcy = tby - (float)gy;
      tww = __logf(tw / c_aw[scale][best] + 1e-6f);
      thh = __logf(th / c_ah[scale][best] + 1e-6f);
      s_cell[tid] = cell;
      s_bit[tid] = 1u << cls[(size_t)b * NT + tid];
    }
    __syncthreads();
    if (tid < NT) {
      // last target with my cell wins; class bits union over all matches
      int win = -1;
      unsigned mask = 0u;
      for (int t = 0; t < NT; ++t)
        if (s_cell[t] == cell) { win = t; mask |= s_bit[t]; }
      if (win == tid) {
        const float* p = plane + cell * 25;
        float aw = c_aw[scale][best], ah = c_ah[scale][best];
        float d0 = sigmoid_f(p[0]) + (float)gx - tcx;
        float d1 = sigmoid_f(p[1]) + (float)gy - tcy;
        float d2 = __expf(p[2]) * aw - tww;
        float d3 = __expf(p[3]) * ah - thh;
        float coord = 5.0f * invN * (d0 * d0 + d1 * d1 + d2 * d2 + d3 * d3);
        float v4 = p[4];
        // add obj conf term, remove the noobj term the stream counted
        float conf = invN * softplus_f(-v4) - 0.5f * invN * softplus_f(v4);
        float csum = 0.0f;
        for (int c = 0; c < NC; ++c) {
          float v = p[5 + c];
          csum += ((mask >> c) & 1u) ? softplus_f(-v) : softplus_f(v);
        }
        acc = (coord + conf + csum * invNC) * (1.0f / 3.0f);
      }
    }
  }

  // ---- block reduction -> per-block partial ----
  for (int off = 32; off > 0; off >>= 1) acc += __shfl_down(acc, off);
  if ((tid & 63) == 0) s_red[tid >> 6] = acc;
  __syncthreads();
  if (tid == 0) ws[bid] = s_red[0] + s_red[1] + s_red[2] + s_red[3];
}

__global__ __launch_bounds__(256) void reduce_kernel(
    const float* __restrict__ ws, float* __restrict__ out) {
  __shared__ float s_red[4];
  int tid = threadIdx.x;
  float v = 0.0f;
  for (int i = tid; i < NBLK; i += 256) v += ws[i];
  for (int off = 32; off > 0; off >>= 1) v += __shfl_down(v, off);
  if ((tid & 63) == 0) s_red[tid >> 6] = v;
  __syncthreads();
  if (tid == 0) out[0] = s_red[0] + s_red[1] + s_red[2] + s_red[3];
}

extern "C" void kernel_launch(void* const* d_in, const int* in_sizes, int n_in,
                              void* d_out, int out_size, void* d_ws, size_t ws_size,
                              hipStream_t stream) {
  const float* pred0 = (const float*)d_in[0];
  const float* pred1 = (const float*)d_in[1];
  const float* pred2 = (const float*)d_in[2];
  const float* boxes = (const float*)d_in[3];
  const int* cls = (const int*)d_in[4];
  float* out = (float*)d_out;
  float* ws = (float*)d_ws;

  yolo_main<<<NBLK, 256, 0, stream>>>(pred0, pred1, pred2, boxes, cls, ws);
  reduce_kernel<<<1, 256, 0, stream>>>(ws, out);
}

// Round 8
// 20.740 us; speedup vs baseline: 3.9812x; 1.0567x over previous
//
#include <hip/hip_runtime.h>
#include <math.h>

#define NT 50
#define NC 20
#define NB 64
#define NCORR 192                 // 3 scales x 64 batches, dispatched FIRST
#define NS0 1585                  // ceil(3244800/2048)
#define NS1 397                   // ceil(811200/2048)
#define NS2 100                   // ceil(202800/2048)
#define NSTREAM (NS0 + NS1 + NS2) // 2082
#define NBLK (NCORR + NSTREAM)    // 2274
#define CHUNK 2048                // float4 per stream block

// anchors / stride per scale: scale0 fs=52 (masks 6,7,8), scale1 fs=26, scale2 fs=13
__device__ __constant__ float c_aw[3][3] = {
    {14.5f, 19.5f, 46.625f},
    {1.875f, 3.875f, 3.6875f},
    {0.3125f, 0.5f, 1.03125f}};
__device__ __constant__ float c_ah[3][3] = {
    {11.25f, 24.75f, 40.75f},
    {3.8125f, 2.8125f, 7.4375f},
    {0.40625f, 0.9375f, 0.71875f}};
// 1/(NB*cells) per scale: cells = 8112, 2028, 507
__device__ __constant__ float c_invN[3] = {
    1.0f / 519168.0f, 1.0f / 129792.0f, 1.0f / 32448.0f};

__device__ __forceinline__ float softplus_f(float x) {
  return __logf(1.0f + __expf(x));  // -log(1-sigmoid(x)) == softplus(x)
}
__device__ __forceinline__ float sigmoid_f(float x) {
  return 1.0f / (1.0f + __expf(-x));
}

__global__ __launch_bounds__(256) void yolo_main(
    const float* __restrict__ pred0, const float* __restrict__ pred1,
    const float* __restrict__ pred2, const float* __restrict__ boxes,
    const int* __restrict__ cls, float* __restrict__ ws) {
  const int bid = blockIdx.x;
  const int tid = threadIdx.x;
  __shared__ float s_red[4];
  float acc = 0.0f;

  if (bid >= NCORR) {
    // ---------------- STREAM: every element treated as noobj ----------------
    // Only channel f%25==4 (conf) contributes: 0.5*invN*softplus(v).
    int sb = bid - NCORR;
    int scale, part, nf4;
    const float* arr;
    if (sb < NS0) { scale = 0; part = sb; arr = pred0; nf4 = 3244800; }
    else if (sb < NS0 + NS1) { scale = 1; part = sb - NS0; arr = pred1; nf4 = 811200; }
    else { scale = 2; part = sb - NS0 - NS1; arr = pred2; nf4 = 202800; }
    const float4* p4 = (const float4*)arr;
    const int base = part * CHUNK;
    const int i0 = base + tid;
    int ch = ((i0 << 2) % 25);  // channel of component .x
    if (base + CHUNK <= nf4) {
      // full chunk: compile-time trip count -> 8 loads in flight
#pragma unroll
      for (int k = 0; k < 8; ++k) {
        float4 v = p4[i0 + 256 * k];
        float vc = (ch == 4) ? v.x : ((ch == 3) ? v.y : ((ch == 2) ? v.z : v.w));
        bool take = (ch >= 1) && (ch <= 4);
        acc += take ? softplus_f(vc) : 0.0f;
        ch = (ch >= 1) ? (ch - 1) : 24;  // advance 1024 floats: -1 mod 25
      }
    } else {
      for (int i = i0; i < nf4; i += 256) {
        float4 v = p4[i];
        float vc = (ch == 4) ? v.x : ((ch == 3) ? v.y : ((ch == 2) ? v.z : v.w));
        bool take = (ch >= 1) && (ch <= 4);
        acc += take ? softplus_f(vc) : 0.0f;
        ch = (ch >= 1) ? (ch - 1) : 24;
      }
    }
    acc *= c_invN[scale] * (0.5f / 3.0f);
  } else {
    // -------------- CORRECTION: exact obj-cell terms, minus over-count -----
    const int scale = bid >> 6;  // 0..2
    const int b = bid & 63;
    const int fs = (scale == 0) ? 52 : ((scale == 1) ? 26 : 13);
    const int cells = fs * fs * 3;
    const float* arr = (scale == 0) ? pred0 : ((scale == 1) ? pred1 : pred2);
    const float* plane = arr + (size_t)b * cells * 25;
    const float invN = c_invN[scale];
    const float invNC = invN * (1.0f / (float)NC);

    __shared__ int s_cell[NT];
    __shared__ unsigned s_bit[NT];

    int cell = -1, gx = 0, gy = 0, best = 0;
    float tcx = 0.f, tcy = 0.f, tww = 0.f, thh = 0.f;
    if (tid < NT) {
      const float* bx = boxes + ((size_t)b * NT + tid) * 4;
      float ffs = (float)fs;
      float tbx = bx[0] * ffs;
      float tby = bx[1] * ffs;
      float tw = bx[2] * ffs;
      float th = bx[3] * ffs;
      float bestr = -1.0f;
      for (int a = 0; a < 3; ++a) {
        float aw = c_aw[scale][a], ah = c_ah[scale][a];
        float inter = fminf(tw, aw) * fminf(th, ah);
        float uni = tw * th + aw * ah - inter;
        float rr = inter / (uni + 1e-6f);
        if (rr > bestr) { bestr = rr; best = a; }
      }
      gx = (int)tbx;
      if (gx < 0) gx = 0;
      if (gx > fs - 1) gx = fs - 1;
      gy = (int)tby;
      if (gy < 0) gy = 0;
      if (gy > fs - 1) gy = fs - 1;
      cell = (gy * fs + gx) * 3 + best;
      tcx = tbx - (float)gx;
      tcy = tby - (float)gy;
      tww = __logf(tw / c_aw[scale][best] + 1e-6f);
      thh = __logf(th / c_ah[scale][best] + 1e-6f);
      s_cell[tid] = cell;
      s_bit[tid] = 1u << cls[(size_t)b * NT + tid];
    }
    __syncthreads();
    if (tid < NT) {
      // last target with my cell wins; class bits union over all matches
      int win = -1;
      unsigned mask = 0u;
      for (int t = 0; t < NT; ++t)
        if (s_cell[t] == cell) { win = t; mask |= s_bit[t]; }
      if (win == tid) {
        const float* p = plane + cell * 25;
        float aw = c_aw[scale][best], ah = c_ah[scale][best];
        float d0 = sigmoid_f(p[0]) + (float)gx - tcx;
        float d1 = sigmoid_f(p[1]) + (float)gy - tcy;
        float d2 = __expf(p[2]) * aw - tww;
        float d3 = __expf(p[3]) * ah - thh;
        float coord = 5.0f * invN * (d0 * d0 + d1 * d1 + d2 * d2 + d3 * d3);
        float v4 = p[4];
        // add obj conf term, remove the noobj term the stream counted
        float conf = invN * softplus_f(-v4) - 0.5f * invN * softplus_f(v4);
        float csum = 0.0f;
        for (int c = 0; c < NC; ++c) {
          float v = p[5 + c];
          csum += ((mask >> c) & 1u) ? softplus_f(-v) : softplus_f(v);
        }
        acc = (coord + conf + csum * invNC) * (1.0f / 3.0f);
      }
    }
  }

  // ---- block reduction -> per-block partial ----
  for (int off = 32; off > 0; off >>= 1) acc += __shfl_down(acc, off);
  if ((tid & 63) == 0) s_red[tid >> 6] = acc;
  __syncthreads();
  if (tid == 0) ws[bid] = s_red[0] + s_red[1] + s_red[2] + s_red[3];
}

__global__ __launch_bounds__(1024) void reduce_kernel(
    const float* __restrict__ ws, float* __restrict__ out) {
  __shared__ float s_red[16];
  int tid = threadIdx.x;
  float v = 0.0f;
  for (int i = tid; i < NBLK; i += 1024) v += ws[i];
  for (int off = 32; off > 0; off >>= 1) v += __shfl_down(v, off);
  if ((tid & 63) == 0) s_red[tid >> 6] = v;
  __syncthreads();
  if (tid == 0) {
    float s = 0.0f;
#pragma unroll
    for (int i = 0; i < 16; ++i) s += s_red[i];
    out[0] = s;
  }
}

extern "C" void kernel_launch(void* const* d_in, const int* in_sizes, int n_in,
                              void* d_out, int out_size, void* d_ws, size_t ws_size,
                              hipStream_t stream) {
  const float* pred0 = (const float*)d_in[0];
  const float* pred1 = (const float*)d_in[1];
  const float* pred2 = (const float*)d_in[2];
  const float* boxes = (const float*)d_in[3];
  const int* cls = (const int*)d_in[4];
  float* out = (float*)d_out;
  float* ws = (float*)d_ws;

  yolo_main<<<NBLK, 256, 0, stream>>>(pred0, pred1, pred2, boxes, cls, ws);
  reduce_kernel<<<1, 1024, 0, stream>>>(ws, out);
}